// Round 1
// 507.327 us; speedup vs baseline: 1.0281x; 1.0281x over previous
//
#include <hip/hip_runtime.h>

// Complete K=8-ary tree, DEPTH=5.
// Level starts: L0:0, L1:1, L2:9, L3:73, L4:585, leaves:4681..37448.
constexpr int NUM_NODES = 37449;
constexpr int L5 = 4681;   // leaf start (32768 leaves)
constexpr int L4 = 585;    // 4096 nodes
constexpr int L3 = 73;     // 512 nodes
constexpr int L2 = 9;      // 64 nodes
constexpr int L1 = 1;      // 8 nodes
constexpr int NLEAF = 32768;

__global__ void sigw_kernel(const float* __restrict__ w, float* __restrict__ sigw) {
    int i = blockIdx.x * blockDim.x + threadIdx.x;
    if (i < NUM_NODES) sigw[i] = 1.0f / (1.0f + __expf(-w[i]));
}

__device__ __forceinline__ float clamp01(float x) {
    return fminf(fmaxf(x, 0.0f), 1.0f);
}

// 16B accessors that are correct at ANY 4B-aligned address.
// Row base = blockIdx*37449 floats, so leaf start is only 4B-aligned
// (alignment mod 16 varies per row). __builtin_memcpy lets the compiler
// emit global_load/store_dwordx4 under gfx950's unaligned-access-mode,
// falling back to dword loads if alignment can't be assumed — never wrong.
struct F4 { float a, b, c, d; };

__device__ __forceinline__ F4 ld4(const float* __restrict__ p) {
    F4 v;
    __builtin_memcpy(&v, p, sizeof(F4));
    return v;
}
__device__ __forceinline__ void st4(float* __restrict__ p, F4 v) {
    __builtin_memcpy(p, &v, sizeof(F4));
}

// One block per batch row. Leaves streamed as float4 (16B/lane, coalesced);
// pairs of lanes own one 8-leaf parent: per-lane dot4, one shfl_xor(1).
// Reduction association matches the original 3-step butterfly exactly:
// ((p0+p1)+(p2+p3)) + ((p4+p5)+(p6+p7)).
__global__ __launch_bounds__(256, 8)
void tree_kernel(const float* __restrict__ in, const float* __restrict__ sigw,
                 float* __restrict__ out) {
    __shared__ float l4s[4096];
    __shared__ float l3s[512];
    __shared__ float l2s[64];
    __shared__ float l1s[8];

    const int t = threadIdx.x;
    const size_t base = (size_t)blockIdx.x * NUM_NODES;
    const float* __restrict__ rin = in + base;
    float* __restrict__ rout = out + base;

    // Stage 1: leaves -> level-4; pass-through copy of leaves.
    // 32768 leaves = 8192 float4 chunks; 256 threads -> 32 iterations.
    #pragma unroll 4
    for (int i = 0; i < 32; ++i) {
        const int v = i * 256 + t;      // float4 chunk id in [0, 8192)
        const int e = v << 2;           // leaf element index (multiple of 4)
        F4 d = ld4(rin + L5 + e);
        F4 s = ld4(sigw + L5 + e);
        st4(rout + L5 + e, d);
        float p0 = d.a * s.a;
        float p1 = d.b * s.b;
        float p2 = d.c * s.c;
        float p3 = d.d * s.d;
        float m = (p0 + p1) + (p2 + p3);
        m += __shfl_xor(m, 1);          // pair covers 8 consecutive leaves
        if ((t & 1) == 0) l4s[v >> 1] = clamp01(m);
    }
    __syncthreads();

    // Stage 2: level-4 -> level-3; write level-4 out (vectorized).
    // 4096 elems = 1024 chunks; 4 iterations.
    #pragma unroll
    for (int i = 0; i < 4; ++i) {
        const int v = i * 256 + t;      // chunk id in [0, 1024)
        const int e = v << 2;
        F4 d;                            // contiguous aligned LDS -> ds_read_b128
        d.a = l4s[e + 0];
        d.b = l4s[e + 1];
        d.c = l4s[e + 2];
        d.d = l4s[e + 3];
        F4 s = ld4(sigw + L4 + e);
        st4(rout + L4 + e, d);
        float p0 = d.a * s.a;
        float p1 = d.b * s.b;
        float p2 = d.c * s.c;
        float p3 = d.d * s.d;
        float m = (p0 + p1) + (p2 + p3);
        m += __shfl_xor(m, 1);
        if ((t & 1) == 0) l3s[v >> 1] = clamp01(m);
    }
    __syncthreads();

    // Stage 3: level-3 -> level-2; write level-3 out. (512 elems — tiny, scalar.)
    for (int i = t; i < 512; i += 256) {
        float v = l3s[i];
        rout[L3 + i] = v;
        float s = v * sigw[L3 + i];
        s += __shfl_xor(s, 1);
        s += __shfl_xor(s, 2);
        s += __shfl_xor(s, 4);
        if ((i & 7) == 0) l2s[i >> 3] = clamp01(s);
    }
    __syncthreads();

    // Stage 4: level-2 -> level-1; write level-2 out.
    if (t < 64) {
        float v = l2s[t];
        rout[L2 + t] = v;
        float s = v * sigw[L2 + t];
        s += __shfl_xor(s, 1);
        s += __shfl_xor(s, 2);
        s += __shfl_xor(s, 4);
        if ((t & 7) == 0) l1s[t >> 3] = clamp01(s);
    }
    __syncthreads();

    // Stage 5: level-1 -> root; write level-1 out.
    if (t < 8) {
        float v = l1s[t];
        rout[L1 + t] = v;
        float s = v * sigw[L1 + t];
        s += __shfl_xor(s, 1);
        s += __shfl_xor(s, 2);
        s += __shfl_xor(s, 4);
        if (t == 0) rout[0] = clamp01(s);
    }
}

extern "C" void kernel_launch(void* const* d_in, const int* in_sizes, int n_in,
                              void* d_out, int out_size, void* d_ws, size_t ws_size,
                              hipStream_t stream) {
    const float* probs = (const float*)d_in[0];   // [batch, NUM_NODES] fp32
    const float* w     = (const float*)d_in[1];   // [NUM_NODES] fp32
    float* out  = (float*)d_out;
    float* sigw = (float*)d_ws;                   // 37449*4 B = 150 KB scratch

    const int batch = in_sizes[0] / NUM_NODES;    // 2048

    hipLaunchKernelGGL(sigw_kernel, dim3((NUM_NODES + 255) / 256), dim3(256), 0,
                       stream, w, sigw);
    hipLaunchKernelGGL(tree_kernel, dim3(batch), dim3(256), 0, stream,
                       probs, sigw, out);
}